// Round 5
// baseline (68.927 us; speedup 1.0000x reference)
//
#include <hip/hip_runtime.h>
#include <math.h>

// Distance: out[b,n,m,{cos,p1,p2}], x[B,N,128], y[M,128], R=B*N rows.
// fp16 LDS tiles + v_dot2_f32_f16 (fp32 accum); p2/cos derived from dot via
// ||x-y||^2 = nx+ny-2dot. Block tile 32n x 32m, thread tile 2x2 -> 1024
// blocks = 4 blocks/CU = 4 waves/SIMD (latency-bound fix vs 2 waves/SIMD).

#define DDIM 128
#define BN 32
#define BM 32
#define PADH 136   // halves per LDS row: 272 B (17*16, b128-aligned), 4-bank skew

typedef __fp16 h2 __attribute__((ext_vector_type(2)));

static __device__ __forceinline__ h2 habs2(h2 v) {
    unsigned u = __builtin_bit_cast(unsigned, v) & 0x7FFF7FFFu;
    return __builtin_bit_cast(h2, u);
}
static __device__ __forceinline__ h2 h2u(unsigned u) {
    return __builtin_bit_cast(h2, u);
}

__global__ __launch_bounds__(256, 4) void distance_kernel(
    const float* __restrict__ x, const float* __restrict__ y,
    float* __restrict__ out, int R, int M)
{
    __shared__ __align__(16) __fp16 xs[BN * PADH];
    __shared__ __align__(16) __fp16 ys[BM * PADH];
    __shared__ float nxs[BN];
    __shared__ float nys[BM];

    const int t  = threadIdx.x;
    const int n0 = blockIdx.x * BN;
    const int m0 = blockIdx.y * BM;

    // ---- Stage tiles: fp32 global -> fp16 LDS (coalesced float4 loads) ----
    {
        const float4* xg = (const float4*)(x + (size_t)n0 * DDIM);
        #pragma unroll
        for (int k = 0; k < (BN * DDIM / 4) / 256; ++k) {   // 4 iters
            int idx = t + 256 * k;
            int row = idx >> 5;
            int c   = idx & 31;
            float4 v = xg[(row << 5) + c];
            h2 h0 = __builtin_amdgcn_cvt_pkrtz(v.x, v.y);
            h2 h1 = __builtin_amdgcn_cvt_pkrtz(v.z, v.w);
            uint2 w;
            w.x = __builtin_bit_cast(unsigned, h0);
            w.y = __builtin_bit_cast(unsigned, h1);
            *(uint2*)&xs[row * PADH + (c << 2)] = w;
        }
        const float4* yg = (const float4*)(y + (size_t)m0 * DDIM);
        #pragma unroll
        for (int k = 0; k < (BM * DDIM / 4) / 256; ++k) {   // 4 iters
            int idx = t + 256 * k;
            int row = idx >> 5;
            int c   = idx & 31;
            float4 v = yg[(row << 5) + c];
            h2 h0 = __builtin_amdgcn_cvt_pkrtz(v.x, v.y);
            h2 h1 = __builtin_amdgcn_cvt_pkrtz(v.z, v.w);
            uint2 w;
            w.x = __builtin_bit_cast(unsigned, h0);
            w.y = __builtin_bit_cast(unsigned, h1);
            *(uint2*)&ys[row * PADH + (c << 2)] = w;
        }
    }
    __syncthreads();

    // ---- Cooperative per-row squared norms (fp32 accum over fp16 tiles) ----
    if (t < BN) {
        float s = 0.f;
        #pragma unroll
        for (int c = 0; c < DDIM / 8; ++c) {
            uint4 v = *(const uint4*)&xs[t * PADH + (c << 3)];
            h2 a = h2u(v.x), b = h2u(v.y), cc2 = h2u(v.z), d = h2u(v.w);
            s = __builtin_amdgcn_fdot2(a, a, s, false);
            s = __builtin_amdgcn_fdot2(b, b, s, false);
            s = __builtin_amdgcn_fdot2(cc2, cc2, s, false);
            s = __builtin_amdgcn_fdot2(d, d, s, false);
        }
        nxs[t] = s;
    } else if (t >= 128 && t < 128 + BM) {
        int row = t - 128;
        float s = 0.f;
        #pragma unroll
        for (int c = 0; c < DDIM / 8; ++c) {
            uint4 v = *(const uint4*)&ys[row * PADH + (c << 3)];
            h2 a = h2u(v.x), b = h2u(v.y), cc2 = h2u(v.z), d = h2u(v.w);
            s = __builtin_amdgcn_fdot2(a, a, s, false);
            s = __builtin_amdgcn_fdot2(b, b, s, false);
            s = __builtin_amdgcn_fdot2(cc2, cc2, s, false);
            s = __builtin_amdgcn_fdot2(d, d, s, false);
        }
        nys[row] = s;
    }
    __syncthreads();

    // ---- Main loop: thread (ln,lm) -> n = n0+ln+16i, m = m0+lm+16j ----
    const int lm = t & 15;
    const int ln = t >> 4;
    const h2 ones = h2u(0x3C003C00u);   // {1.0h, 1.0h}

    float dot[2][2] = {};
    float p1 [2][2] = {};

    #pragma unroll 4
    for (int c = 0; c < DDIM / 8; ++c) {           // 16 chunks of 8 dims
        uint4 xv[2], yv[2];
        xv[0] = *(const uint4*)&xs[ ln       * PADH + (c << 3)];
        xv[1] = *(const uint4*)&xs[(ln + 16) * PADH + (c << 3)];
        yv[0] = *(const uint4*)&ys[ lm       * PADH + (c << 3)];
        yv[1] = *(const uint4*)&ys[(lm + 16) * PADH + (c << 3)];

        #pragma unroll
        for (int i = 0; i < 2; ++i) {
            #pragma unroll
            for (int j = 0; j < 2; ++j) {
                const unsigned* xw = (const unsigned*)&xv[i];
                const unsigned* yw = (const unsigned*)&yv[j];
                #pragma unroll
                for (int k = 0; k < 4; ++k) {
                    h2 xh = h2u(xw[k]);
                    h2 yh = h2u(yw[k]);
                    h2 d  = xh - yh;
                    dot[i][j] = __builtin_amdgcn_fdot2(xh, yh, dot[i][j], false);
                    p1 [i][j] = __builtin_amdgcn_fdot2(habs2(d), ones, p1[i][j], false);
                }
            }
        }
    }

    // ---- Epilogue: cos = dot*rsqrt(nx*ny); p2 = sqrt(nx+ny-2dot) ----
    #pragma unroll
    for (int i = 0; i < 2; ++i) {
        int n = n0 + ln + 16 * i;
        float nx = nxs[ln + 16 * i];
        #pragma unroll
        for (int j = 0; j < 2; ++j) {
            int m = m0 + lm + 16 * j;
            float ny = nys[lm + 16 * j];
            float d  = dot[i][j];
            float* o = out + ((size_t)n * M + m) * 3;
            o[0] = d * rsqrtf(nx * ny);
            o[1] = p1[i][j];
            o[2] = sqrtf(fmaxf(nx + ny - 2.f * d, 0.f));
        }
    }
}

extern "C" void kernel_launch(void* const* d_in, const int* in_sizes, int n_in,
                              void* d_out, int out_size, void* d_ws, size_t ws_size,
                              hipStream_t stream) {
    const float* x = (const float*)d_in[0];
    const float* y = (const float*)d_in[1];
    float* out = (float*)d_out;

    const int R = in_sizes[0] / DDIM;   // B*N = 2048
    const int M = in_sizes[1] / DDIM;   // 512

    dim3 grid(R / BN, M / BM);          // (64, 16) = 1024 blocks, 4/CU
    distance_kernel<<<grid, 256, 0, stream>>>(x, y, out, R, M);
}